// Round 6
// baseline (274.942 us; speedup 1.0000x reference)
//
#include <hip/hip_runtime.h>
#include <stdint.h>

typedef uint32_t u32;
typedef uint64_t u64;

#define BN 16
#define CLS 80
#define ROWF 85
#define KSEL 512
#define NBKT 4096
#define R1 64
#define CONF_T 0.001f
#define NMS_T 0.5f

__device__ __forceinline__ u32 flip_desc(float x) {
    u32 u = __float_as_uint(x);
    u32 m = (u & 0x80000000u) ? ~u : (u | 0x80000000u); // monotonic ascending
    return ~m;                                          // descending key
}
__device__ __forceinline__ float unflip(u32 key) {
    u32 m = ~key;
    u32 u = (m & 0x80000000u) ? (m & 0x7fffffffu) : ~m;
    return __uint_as_float(u);
}
__device__ __forceinline__ int conf_bucket(float cm) {
    float f = floorf(cm * 4096.0f);
    f = fminf(f, 4095.0f);
    f = fmaxf(f, 0.0f);
    return (int)f;
}

// ---------------- K1: per-row conf key; 64-row tiles; zero hist/cnt ----------------
__global__ __launch_bounds__(256) void k1_keys(const float* __restrict__ pred,
                                               u32* __restrict__ keys,
                                               u32* __restrict__ hist,
                                               u32* __restrict__ cnt, int totalRows) {
    __shared__ float buf[R1 * ROWF]; // 21,760 B -> 7 blocks/CU
    if (blockIdx.x < 256) {          // zero global hist (16*4096) + cnt before k2a
        hist[blockIdx.x * 256 + threadIdx.x] = 0;
        if (blockIdx.x == 0 && threadIdx.x < BN * 2) cnt[threadIdx.x] = 0;
    }
    int row0 = blockIdx.x * R1;
    int nrow = min(R1, totalRows - row0);
    if (nrow <= 0) return;
    int nf4 = nrow * ROWF / 4; // 64|48 rows * 85 floats divisible by 4
    const float4* p4 = (const float4*)(pred + (long long)row0 * ROWF);
    float4* b4 = (float4*)buf;
    for (int k = threadIdx.x; k < nf4; k += 256) b4[k] = p4[k];
    __syncthreads();
    int r = threadIdx.x;
    if (r < nrow) {
        const float* p = &buf[r * ROWF];
        float obj = p[4];
        float mx = p[5];
        #pragma unroll
        for (int c = 1; c < CLS; c++) { float v = p[5 + c]; if (v > mx) mx = v; }
        float conf = obj * mx;
        float w = p[2], h = p[3];
        bool ok = (conf > CONF_T) && (w > 2.0f) && (w < 10000.0f) && (h > 2.0f) && (h < 10000.0f);
        bool fin = true;
        #pragma unroll
        for (int c = 0; c < ROWF; c++) {
            u32 bb = __float_as_uint(p[c]);
            if ((bb & 0x7f800000u) == 0x7f800000u) fin = false;
        }
        ok = ok && fin;
        float cm = ok ? conf : -1.0f;
        keys[row0 + r] = flip_desc(cm);
    }
}

// ---------------- K2a: per-image value histogram, 16 blocks/image, LDS-accumulated ----------------
__global__ __launch_bounds__(256) void k2a_hist(const u32* __restrict__ keys,
                                                u32* __restrict__ hist, int N) {
    int b = blockIdx.x >> 4;
    int chunk = blockIdx.x & 15;
    __shared__ u32 lh[NBKT]; // 16KB
    int tid = threadIdx.x;
    for (int i = tid; i < NBKT; i += 256) lh[i] = 0;
    __syncthreads();
    const u32* kk = keys + (long long)b * N;
    for (int i = chunk * 256 + tid; i < N; i += 4096)
        atomicAdd(&lh[conf_bucket(unflip(kk[i]))], 1u);
    __syncthreads();
    for (int i = tid; i < NBKT; i += 256) {
        u32 v = lh[i];
        if (v) atomicAdd(&hist[b * NBKT + i], v);
    }
}

// ---------------- K2bc: per-block redundant threshold + compaction slice ----------------
__global__ __launch_bounds__(256) void k2bc(const u32* __restrict__ keys,
                                            const u32* __restrict__ hist,
                                            u32* __restrict__ tbinfo,
                                            u32* __restrict__ cnt,
                                            u64* __restrict__ above,
                                            u64* __restrict__ ties, int N) {
    int b = blockIdx.x >> 4;
    int chunk = blockIdx.x & 15;
    const u32* H = hist + b * NBKT;
    __shared__ u32 part[256];
    __shared__ u32 pre[256];
    __shared__ u32 sh_Tb, sh_nA;
    int t = threadIdx.x;
    // threshold scan from top (identical in all 16 blocks of this image)
    u32 s = 0;
    #pragma unroll
    for (int k = 0; k < 16; k++) s += H[NBKT - 1 - (t * 16 + k)];
    part[t] = s;
    __syncthreads();
    if (t == 0) { u32 c = 0; for (int i = 0; i < 256; i++) { pre[i] = c; c += part[i]; } }
    __syncthreads();
    {
        u32 cum = pre[t];
        if (cum < KSEL && cum + part[t] >= KSEL) { // unique crossing thread
            for (int k = 0; k < 16; k++) {
                int bidx = NBKT - 1 - (t * 16 + k);
                u32 h = H[bidx];
                if (cum + h >= KSEL) { sh_Tb = (u32)bidx; sh_nA = cum; break; }
                cum += h;
            }
        }
    }
    __syncthreads();
    u32 Tb = sh_Tb;
    if (chunk == 0 && t == 0) { tbinfo[b * 2] = Tb; tbinfo[b * 2 + 1] = sh_nA; }
    // compact this block's slice
    const u32* kk = keys + (long long)b * N;
    u64* av = above + b * KSEL;
    u64* tv = ties + (long long)b * N;
    for (int i = chunk * 256 + t; i < N; i += 4096) {
        u32 e = kk[i];
        u32 bk = (u32)conf_bucket(unflip(e));
        if (bk > Tb) {
            u32 p = atomicAdd(&cnt[b * 2], 1u);
            av[p] = ((u64)e << 32) | (u32)i;
        } else if (bk == Tb) {
            u32 p = atomicAdd(&cnt[b * 2 + 1], 1u);
            tv[p] = ((u64)e << 32) | (u32)i;
        }
    }
}

// ---------------- KBig: select + sort + gather + IoU + NMS scan + output, 1 block/image ----------------
__global__ __launch_bounds__(256) void kbig(const float* __restrict__ pred,
                                            const u64* __restrict__ above,
                                            const u64* __restrict__ ties,
                                            const u32* __restrict__ tbinfo,
                                            const u32* __restrict__ cnt,
                                            float* __restrict__ out, int N) {
    int b = blockIdx.x;
    int tid = threadIdx.x;
    int lane = tid & 63;
    int wv = tid >> 6;
    __shared__ float S[KSEL * 8];        // 16KB
    __shared__ u64 MT[8 * KSEL];         // 32KB  [w][i]
    __shared__ float MG[KSEL * 4];       // 8KB
    __shared__ unsigned short TGT[KSEL]; // 1KB
    __shared__ u64 skey[KSEL];           // 4KB
    __shared__ u32 h256[256];            // 1KB
    __shared__ u64 sh_pfx;
    __shared__ u32 sh_rem, sh_cnt2;
    __shared__ u64 sh_keep[8], sh_ok[8];

    // ---- phase A: assemble top-512 (above + tie-select) then bitonic sort ----
    u32 nA = tbinfo[b * 2 + 1];
    u32 ntie = cnt[b * 2 + 1];
    u32 tsel = KSEL - nA;
    const u64* av = above + b * KSEL;
    const u64* tv = ties + (long long)b * N;
    for (u32 i = tid; i < nA; i += 256) skey[i] = av[i];
    if (ntie == tsel) {
        for (u32 j = tid; j < tsel; j += 256) skey[nA + j] = tv[j];
    } else {
        // exact radix select: tsel-th smallest u64 among ties (all distinct: low32 unique idx)
        if (tid == 0) { sh_pfx = 0; sh_rem = tsel; }
        for (int byte = 7; byte >= 0; byte--) {
            __syncthreads();
            h256[tid] = 0;
            __syncthreads();
            u64 pfx = sh_pfx;
            for (u32 i = tid; i < ntie; i += 256) {
                u64 e = tv[i];
                if (byte == 7 || (e >> ((byte + 1) * 8)) == pfx)
                    atomicAdd(&h256[(u32)(e >> (byte * 8)) & 255u], 1u);
            }
            __syncthreads();
            if (tid == 0) {
                u32 rem = sh_rem, cum = 0; int c = 0;
                for (; c < 256; c++) { if (cum + h256[c] >= rem) break; cum += h256[c]; }
                sh_rem = rem - cum;
                sh_pfx = (pfx << 8) | (u32)c;
            }
        }
        __syncthreads();
        u64 Tu = sh_pfx;
        if (tid == 0) sh_cnt2 = 0;
        __syncthreads();
        for (u32 i = tid; i < ntie; i += 256) {
            u64 e = tv[i];
            if (e <= Tu) { u32 p = atomicAdd(&sh_cnt2, 1u); skey[nA + p] = e; }
        }
    }
    __syncthreads();
    for (int k = 2; k <= KSEL; k <<= 1) { // bitonic: conf desc, idx asc (== lax.top_k)
        for (int j = k >> 1; j > 0; j >>= 1) {
            for (int i = tid; i < KSEL; i += 256) {
                int l = i ^ j;
                if (l > i) {
                    bool dir = ((i & k) == 0);
                    u64 a = skey[i], c = skey[l];
                    if ((a > c) == dir) { skey[i] = c; skey[l] = a; }
                }
            }
            __syncthreads();
        }
    }

    // ---- phase B: gather rows -> S (LDS) ----
    for (int g = tid; g < KSEL; g += 256) {
        int idx = (int)(skey[g] & 0xffffffffu);
        const float* row = pred + ((long long)b * N + idx) * ROWF;
        float obj = row[4];
        float mx = row[5]; int am = 0;
        for (int c = 1; c < CLS; c++) { float v = row[5 + c]; if (v > mx) { mx = v; am = c; } }
        float conf = obj * mx;
        float cx = row[0], cy = row[1], w = row[2], h = row[3];
        bool ok = (conf > CONF_T) && (w > 2.0f) && (w < 10000.0f) && (h > 2.0f) && (h < 10000.0f);
        bool fin = true;
        for (int c = 0; c < ROWF; c++) {
            u32 bb = __float_as_uint(row[c]);
            if ((bb & 0x7f800000u) == 0x7f800000u) fin = false;
        }
        ok = ok && fin;
        float off = (float)am * 10000.0f;
        float x1 = cx - w * 0.5f, y1 = cy - h * 0.5f;
        float x2 = cx + w * 0.5f, y2 = cy + h * 0.5f;
        float* s = &S[g * 8];
        s[0] = x1 + off; s[1] = y1; s[2] = x2 + off; s[3] = y2;
        s[4] = conf; s[5] = mx; s[6] = (float)am; s[7] = ok ? 1.0f : 0.0f;
    }
    __syncthreads();

    // ---- phase C: IoU bitmatrix in LDS ----
    #pragma unroll 1
    for (int ww = 0; ww < 16; ww++) {
        int widx = ww * 256 + tid; // [0,4096)
        int w = widx >> 9;
        int i = widx & (KSEL - 1);
        float x1 = S[i * 8 + 0], y1 = S[i * 8 + 1], x2 = S[i * 8 + 2], y2 = S[i * 8 + 3];
        float a1 = __fmul_rn(__fsub_rn(x2, x1), __fsub_rn(y2, y1));
        u64 bits = 0;
        int j0 = w * 64;
        for (int jj = 0; jj < 64; jj++) {
            const float* bj = &S[(j0 + jj) * 8]; // uniform within wave halves -> broadcast-ish
            float ix = fmaxf(__fsub_rn(fminf(x2, bj[2]), fmaxf(x1, bj[0])), 0.0f);
            float iy = fmaxf(__fsub_rn(fminf(y2, bj[3]), fmaxf(y1, bj[1])), 0.0f);
            float inter = __fmul_rn(ix, iy);
            float a2 = __fmul_rn(__fsub_rn(bj[2], bj[0]), __fsub_rn(bj[3], bj[1]));
            float denom = __fadd_rn(__fsub_rn(__fadd_rn(a1, a2), inter), 1e-9f);
            float iou = __fdiv_rn(inter, denom);
            if (iou > NMS_T) bits |= (1ull << jj);
        }
        MT[(long long)w * KSEL + i] = bits;
    }
    __syncthreads();

    // ---- phase D: chunked scalar keep-scan (wave 0) ----
    if (wv == 0) {
        u32 a_bits = 0; // bit w = column (w*64+lane) alive
        #pragma unroll
        for (int w = 0; w < 8; w++)
            if (S[(w * 64 + lane) * 8 + 7] > 0.5f) a_bits |= 1u << w;
        #pragma unroll
        for (int w = 0; w < 8; w++) {
            u64 ow = __ballot((a_bits >> w) & 1u);
            if (lane == 0) sh_ok[w] = ow;
        }
        #pragma unroll 1
        for (int c = 0; c < 8; c++) {
            u64 cross[8];
            #pragma unroll
            for (int w = 0; w < 8; w++) cross[w] = MT[c * KSEL + w * 64 + lane];
            u64 intra = MT[c * KSEL + c * 64 + lane];
            u64 aliveC = __ballot((a_bits >> c) & 1u);
            u32 ilo = (u32)intra, ihi = (u32)(intra >> 32);
            u64 keptC = 0;
            #pragma unroll
            for (int m = 0; m < 64; m++) { // symmetric matrix: row m == lane m's column word
                u32 rl = __builtin_amdgcn_readlane(ilo, m);
                u32 rh = __builtin_amdgcn_readlane(ihi, m);
                u64 rowm = ((u64)rh << 32) | rl;
                u64 take = (aliveC >> m) & 1ull;
                u64 msk = (u64)0 - take;
                keptC |= take << m;
                aliveC &= ~(rowm & msk);
            }
            if (lane == 0) sh_keep[c] = keptC;
            #pragma unroll
            for (int w = 0; w < 8; w++)
                if (cross[w] & keptC) a_bits &= ~(1u << w);
        }
    }
    __syncthreads();
    u64 keepW[8], okW[8];
    #pragma unroll
    for (int w = 0; w < 8; w++) { keepW[w] = sh_keep[w]; okW[w] = sh_ok[w]; }

    // ---- phase E1: per-column merge target = first kept bit of row j (M symmetric) ----
    for (int j = tid; j < KSEL; j += 256) {
        int r = j >> 6, ln = j & 63;
        int tgt = 0xffff;
        if ((okW[r] >> ln) & 1ull) {
            #pragma unroll
            for (int w = 7; w >= 0; w--) {
                u64 m = MT[w * KSEL + j] & keepW[w];
                if (m) tgt = w * 64 + (int)__builtin_ctzll(m);
            }
        }
        TGT[j] = (unsigned short)tgt;
    }
    __syncthreads();

    // ---- phase E2: per kept k, deterministic ascending-j weighted merge ----
    for (int k = tid; k < KSEL; k += 256) {
        int r = k >> 6, ln = k & 63;
        if ((keepW[r] >> ln) & 1ull) {
            float s0 = 0.f, s1 = 0.f, s2 = 0.f, s3 = 0.f, sw = 0.f;
            #pragma unroll 1
            for (int w = 0; w < 8; w++) {
                u64 m = MT[w * KSEL + k] & okW[w];
                while (m) {
                    int j = w * 64 + (int)__builtin_ctzll(m);
                    m &= m - 1;
                    if (TGT[j] == (unsigned short)k) {
                        float c = S[j * 8 + 4];
                        s0 += c * S[j * 8 + 0]; s1 += c * S[j * 8 + 1];
                        s2 += c * S[j * 8 + 2]; s3 += c * S[j * 8 + 3];
                        sw += c;
                    }
                }
            }
            float d = sw + 1e-12f;
            MG[k * 4 + 0] = s0 / d; MG[k * 4 + 1] = s1 / d;
            MG[k * 4 + 2] = s2 / d; MG[k * 4 + 3] = s3 / d;
        }
    }
    __syncthreads();

    // ---- output: compact kept rows in order, zero tail ----
    int nk = 0;
    #pragma unroll
    for (int w = 0; w < 8; w++) nk += __popcll(keepW[w]);
    float* ob = out + (long long)b * KSEL * 7;
    for (int i = tid; i < KSEL; i += 256) {
        int wi = i >> 6, bi = i & 63;
        if ((keepW[wi] >> bi) & 1ull) {
            int rank = 0;
            for (int w = 0; w < wi; w++) rank += __popcll(keepW[w]);
            rank += __popcll(keepW[wi] & ((1ull << bi) - 1ull));
            float off = S[i * 8 + 6] * 10000.0f;
            float* o = ob + rank * 7;
            o[0] = MG[i * 4 + 0] - off; o[1] = MG[i * 4 + 1];
            o[2] = MG[i * 4 + 2] - off; o[3] = MG[i * 4 + 3];
            o[4] = S[i * 8 + 4]; o[5] = S[i * 8 + 5]; o[6] = S[i * 8 + 6];
        }
    }
    for (int p = nk + tid; p < KSEL; p += 256) {
        float* o = ob + p * 7;
        #pragma unroll
        for (int c = 0; c < 7; c++) o[c] = 0.0f;
    }
}

extern "C" void kernel_launch(void* const* d_in, const int* in_sizes, int n_in,
                              void* d_out, int out_size, void* d_ws, size_t ws_size,
                              hipStream_t stream) {
    const float* pred = (const float*)d_in[0];
    float* out = (float*)d_out;
    int total = in_sizes[0];
    int N = total / (BN * ROWF); // 22743
    int totalRows = BN * N;

    char* ws = (char*)d_ws;
    size_t o = 0;
    u32* hist = (u32*)(ws + o);   o += (size_t)BN * NBKT * 4; // 256KB
    u32* cnt = (u32*)(ws + o);    o += (size_t)BN * 2 * 4;
    u32* tbinfo = (u32*)(ws + o); o += (size_t)BN * 2 * 4;
    u32* keys = (u32*)(ws + o);   o += (size_t)totalRows * 4;
    u64* above = (u64*)(ws + o);  o += (size_t)BN * KSEL * 8;
    u64* ties = (u64*)(ws + o);   o += (size_t)BN * N * 8;
    (void)ws_size;

    k1_keys<<<(totalRows + R1 - 1) / R1, 256, 0, stream>>>(pred, keys, hist, cnt, totalRows);
    k2a_hist<<<BN * 16, 256, 0, stream>>>(keys, hist, N);
    k2bc<<<BN * 16, 256, 0, stream>>>(keys, hist, tbinfo, cnt, above, ties, N);
    kbig<<<BN, 256, 0, stream>>>(pred, above, ties, tbinfo, cnt, out, N);
}

// Round 7
// 273.588 us; speedup vs baseline: 1.0049x; 1.0049x over previous
//
#include <hip/hip_runtime.h>
#include <stdint.h>

typedef uint32_t u32;
typedef uint64_t u64;

#define BN 16
#define CLS 80
#define ROWF 85
#define KSEL 512
#define NBKT 4096
#define NBLK 256
#define NTHR 512
#define TILE 128
#define CONF_T 0.001f
#define NMS_T 0.5f

__device__ __forceinline__ u32 flip_desc(float x) {
    u32 u = __float_as_uint(x);
    u32 m = (u & 0x80000000u) ? ~u : (u | 0x80000000u); // monotonic ascending
    return ~m;                                          // descending key
}
__device__ __forceinline__ float unflip(u32 key) {
    u32 m = ~key;
    u32 u = (m & 0x80000000u) ? (m & 0x7fffffffu) : ~m;
    return __uint_as_float(u);
}
__device__ __forceinline__ int conf_bucket(float cm) {
    float f = floorf(cm * 4096.0f);
    f = fminf(f, 4095.0f);
    f = fmaxf(f, 0.0f);
    return (int)f;
}

// one-shot device-scope grid barrier (bar[] zeroed by hipMemsetAsync each call)
__device__ __forceinline__ void gridbar(u32* bar, int idx) {
    __syncthreads();
    if (threadIdx.x == 0) {
        __threadfence();                 // release (agent scope: wb L2)
        atomicAdd(&bar[idx], 1u);        // device-scope RMW at coherent point
        while (__hip_atomic_load(&bar[idx], __ATOMIC_RELAXED,
                                 __HIP_MEMORY_SCOPE_AGENT) < (u32)NBLK)
            __builtin_amdgcn_s_sleep(8);
        __threadfence();                 // acquire (inv caches)
    }
    __syncthreads();
}

__global__ __launch_bounds__(NTHR) void coop(
        const float* __restrict__ pred, u32* __restrict__ keys,
        u32* __restrict__ hist, u32* __restrict__ cnt,
        u64* __restrict__ above, u64* __restrict__ ties,
        u32* __restrict__ selidx, float* __restrict__ sel,
        u64* __restrict__ matT, float* __restrict__ out,
        u32* __restrict__ bar, int N, int totalRows) {

    __shared__ __align__(16) unsigned char LDSU[59392]; // 58 KB union
    __shared__ u32 sh_Tb, sh_nA, sh_rem, sh_cnt2;
    __shared__ u64 sh_pfx;
    __shared__ u64 sh_keep[8], sh_ok[8];

    const int j = blockIdx.x;
    const int tid = threadIdx.x;

    // ================= P1a: keys (+ zero hist/cnt) =================
    {
        int zi = j * NTHR + tid;
        if (zi < BN * NBKT) hist[zi] = 0;
        if (zi < BN * 2) cnt[zi] = 0;

        float* stage = (float*)LDSU; // 43.5 KB (128 rows)
        int T = (totalRows + TILE - 1) / TILE;
        int t0 = (int)(((long long)j * T) / NBLK);
        int t1 = (int)(((long long)(j + 1) * T) / NBLK);
        for (int tt = t0; tt < t1; tt++) {
            int row0 = tt * TILE;
            int nrow = min(TILE, totalRows - row0);
            int nf4 = nrow * ROWF / 4; // 128|112 rows * 85 -> /4 exact
            const float4* p4 = (const float4*)(pred + (long long)row0 * ROWF);
            float4* b4 = (float4*)stage;
            __syncthreads();
            for (int k = tid; k < nf4; k += NTHR) b4[k] = p4[k];
            __syncthreads();
            if (tid < nrow) {
                const float* p = &stage[tid * ROWF];
                float obj = p[4];
                float mx = p[5];
                #pragma unroll
                for (int c = 1; c < CLS; c++) { float v = p[5 + c]; if (v > mx) mx = v; }
                float conf = obj * mx;
                float w = p[2], h = p[3];
                bool ok = (conf > CONF_T) && (w > 2.0f) && (w < 10000.0f) && (h > 2.0f) && (h < 10000.0f);
                bool fin = true;
                #pragma unroll
                for (int c = 0; c < ROWF; c++) {
                    u32 bb = __float_as_uint(p[c]);
                    if ((bb & 0x7f800000u) == 0x7f800000u) fin = false;
                }
                ok = ok && fin;
                keys[row0 + tid] = flip_desc(ok ? conf : -1.0f);
            }
        }
    }
    gridbar(bar, 0);

    // ================= P1b: per-image value histogram =================
    {
        u32* lh = (u32*)LDSU; // 16 KB
        for (int i = tid; i < NBKT; i += NTHR) lh[i] = 0;
        __syncthreads();
        int b = j >> 4, c = j & 15;
        int CH = (N + 15) / 16;
        const u32* kk = keys + (long long)b * N;
        int r1 = min(N, (c + 1) * CH);
        for (int i = c * CH + tid; i < r1; i += NTHR)
            atomicAdd(&lh[conf_bucket(unflip(kk[i]))], 1u);
        __syncthreads();
        for (int i = tid; i < NBKT; i += NTHR) {
            u32 v = lh[i];
            if (v) atomicAdd(&hist[b * NBKT + i], v);
        }
    }
    gridbar(bar, 1);

    // ================= P2: redundant threshold + compact =================
    {
        int b = j >> 4, c = j & 15;
        const u32* H = hist + b * NBKT;
        u32* part = (u32*)LDSU;          // 2 KB
        u32* pre  = (u32*)(LDSU + 2048); // 2 KB
        u32 s = 0;
        #pragma unroll
        for (int k = 0; k < 8; k++) s += H[NBKT - 1 - (tid * 8 + k)];
        part[tid] = s;
        __syncthreads();
        if (tid == 0) { u32 cc = 0; for (int i = 0; i < NTHR; i++) { pre[i] = cc; cc += part[i]; } }
        __syncthreads();
        {
            u32 cum = pre[tid];
            if (cum < KSEL && cum + part[tid] >= KSEL) { // unique crossing thread
                for (int k = 0; k < 8; k++) {
                    int bidx = NBKT - 1 - (tid * 8 + k);
                    u32 h = H[bidx];
                    if (cum + h >= KSEL) { sh_Tb = (u32)bidx; sh_nA = cum; break; }
                    cum += h;
                }
            }
        }
        __syncthreads();
        u32 Tb = sh_Tb;
        int CH = (N + 15) / 16;
        const u32* kk = keys + (long long)b * N;
        u64* av = above + b * KSEL;
        u64* tv = ties + (long long)b * N;
        int r1 = min(N, (c + 1) * CH);
        for (int i = c * CH + tid; i < r1; i += NTHR) {
            u32 e = kk[i];
            u32 bk = (u32)conf_bucket(unflip(e));
            if (bk > Tb) { u32 p = atomicAdd(&cnt[b * 2], 1u); av[p] = ((u64)e << 32) | (u32)i; }
            else if (bk == Tb) { u32 p = atomicAdd(&cnt[b * 2 + 1], 1u); tv[p] = ((u64)e << 32) | (u32)i; }
        }
    }
    gridbar(bar, 2);

    // ================= P3: tie-select + bitonic sort (16 blocks) =================
    if (j < BN) {
        int b = j;
        const u32* H = hist + b * NBKT;
        u64* skey = (u64*)LDSU;               // 4 KB
        u32* part = (u32*)(LDSU + 8192);
        u32* pre  = (u32*)(LDSU + 10240);
        u32* h256 = (u32*)(LDSU + 12288);
        u32 s = 0;
        #pragma unroll
        for (int k = 0; k < 8; k++) s += H[NBKT - 1 - (tid * 8 + k)];
        part[tid] = s;
        __syncthreads();
        if (tid == 0) { u32 cc = 0; for (int i = 0; i < NTHR; i++) { pre[i] = cc; cc += part[i]; } }
        __syncthreads();
        {
            u32 cum = pre[tid];
            if (cum < KSEL && cum + part[tid] >= KSEL) {
                for (int k = 0; k < 8; k++) {
                    int bidx = NBKT - 1 - (tid * 8 + k);
                    u32 h = H[bidx];
                    if (cum + h >= KSEL) { sh_nA = cum; break; }
                    cum += h;
                }
            }
        }
        __syncthreads();
        u32 nA = sh_nA;
        u32 ntie = cnt[b * 2 + 1];
        u32 tsel = KSEL - nA;
        const u64* av = above + b * KSEL;
        const u64* tv = ties + (long long)b * N;
        for (u32 i = tid; i < nA; i += NTHR) skey[i] = av[i];
        if (ntie == tsel) {
            for (u32 i = tid; i < tsel; i += NTHR) skey[nA + i] = tv[i];
        } else {
            // exact radix select: tsel-th smallest u64 (all distinct: low32 = unique idx)
            if (tid == 0) { sh_pfx = 0; sh_rem = tsel; }
            for (int byte = 7; byte >= 0; byte--) {
                __syncthreads();
                if (tid < 256) h256[tid] = 0;
                __syncthreads();
                u64 pfx = sh_pfx;
                for (u32 i = tid; i < ntie; i += NTHR) {
                    u64 e = tv[i];
                    if (byte == 7 || (e >> ((byte + 1) * 8)) == pfx)
                        atomicAdd(&h256[(u32)(e >> (byte * 8)) & 255u], 1u);
                }
                __syncthreads();
                if (tid == 0) {
                    u32 rem = sh_rem, cum = 0; int c = 0;
                    for (; c < 256; c++) { if (cum + h256[c] >= rem) break; cum += h256[c]; }
                    sh_rem = rem - cum;
                    sh_pfx = (pfx << 8) | (u32)c;
                }
            }
            __syncthreads();
            u64 Tu = sh_pfx;
            if (tid == 0) sh_cnt2 = 0;
            __syncthreads();
            for (u32 i = tid; i < ntie; i += NTHR) {
                u64 e = tv[i];
                if (e <= Tu) { u32 p = atomicAdd(&sh_cnt2, 1u); skey[nA + p] = e; }
            }
        }
        __syncthreads();
        for (int k = 2; k <= KSEL; k <<= 1) { // conf desc, idx asc == lax.top_k
            for (int jj = k >> 1; jj > 0; jj >>= 1) {
                int i = tid;
                if (i < KSEL) {
                    int l = i ^ jj;
                    if (l > i) {
                        bool dir = ((i & k) == 0);
                        u64 a = skey[i], c2 = skey[l];
                        if ((a > c2) == dir) { skey[i] = c2; skey[l] = a; }
                    }
                }
                __syncthreads();
            }
        }
        for (int i = tid; i < KSEL; i += NTHR) selidx[b * KSEL + i] = (u32)(skey[i] & 0xffffffffu);
    }
    gridbar(bar, 3);

    // ================= P4: gather (16 blocks x 512 = 1 row/thread) =================
    if (j < BN) {
        int b = j;
        int idx = (int)selidx[b * KSEL + tid];
        const float* row = pred + ((long long)b * N + idx) * ROWF;
        float obj = row[4];
        float mx = row[5]; int am = 0;
        for (int c = 1; c < CLS; c++) { float v = row[5 + c]; if (v > mx) { mx = v; am = c; } }
        float conf = obj * mx;
        float cx = row[0], cy = row[1], w = row[2], h = row[3];
        bool ok = (conf > CONF_T) && (w > 2.0f) && (w < 10000.0f) && (h > 2.0f) && (h < 10000.0f);
        bool fin = true;
        for (int c = 0; c < ROWF; c++) {
            u32 bb = __float_as_uint(row[c]);
            if ((bb & 0x7f800000u) == 0x7f800000u) fin = false;
        }
        ok = ok && fin;
        float off = (float)am * 10000.0f;
        float x1 = cx - w * 0.5f, y1 = cy - h * 0.5f;
        float x2 = cx + w * 0.5f, y2 = cy + h * 0.5f;
        float* s = sel + ((long long)b * KSEL + tid) * 8;
        s[0] = x1 + off; s[1] = y1; s[2] = x2 + off; s[3] = y2;
        s[4] = conf; s[5] = mx; s[6] = (float)am; s[7] = ok ? 1.0f : 0.0f;
    }
    gridbar(bar, 4);

    // ================= P5: IoU bitmatrix (128 blocks, 1 word/thread) =================
    if (j < 128) {
        int b = j >> 3;
        int w = j & 7;
        float* BX = (float*)LDSU; // 8 KB
        const float4* S4 = (const float4*)(sel + (long long)b * KSEL * 8);
        float4* B4 = (float4*)BX;
        B4[tid] = S4[tid * 2];
        __syncthreads();
        int i = tid;
        float x1 = BX[i * 4 + 0], y1 = BX[i * 4 + 1], x2 = BX[i * 4 + 2], y2 = BX[i * 4 + 3];
        float a1 = __fmul_rn(__fsub_rn(x2, x1), __fsub_rn(y2, y1));
        u64 bits = 0;
        int j0 = w * 64;
        const float4* BB = (const float4*)BX;
        for (int jj = 0; jj < 64; jj++) {
            float4 bj = BB[j0 + jj]; // broadcast: block shares w
            float ix = fmaxf(__fsub_rn(fminf(x2, bj.z), fmaxf(x1, bj.x)), 0.0f);
            float iy = fmaxf(__fsub_rn(fminf(y2, bj.w), fmaxf(y1, bj.y)), 0.0f);
            float inter = __fmul_rn(ix, iy);
            float a2 = __fmul_rn(__fsub_rn(bj.z, bj.x), __fsub_rn(bj.w, bj.y));
            float denom = __fadd_rn(__fsub_rn(__fadd_rn(a1, a2), inter), 1e-9f);
            float iou = __fdiv_rn(inter, denom);
            if (iou > NMS_T) bits |= (1ull << jj);
        }
        matT[((long long)b * 8 + w) * KSEL + i] = bits;
    }
    gridbar(bar, 5);

    // ================= P6: NMS scan + merge + output (16 blocks) =================
    if (j < BN) {
        int b = j;
        int lane = tid & 63;
        int wv = tid >> 6;
        float* S = (float*)LDSU;                                // 16 KB
        u64* MT = (u64*)(LDSU + 16384);                         // 32 KB [w][i]
        float* MG = (float*)(LDSU + 49152);                     // 8 KB
        unsigned short* TGT = (unsigned short*)(LDSU + 57344);  // 1 KB
        const float4* gs = (const float4*)(sel + (long long)b * KSEL * 8);
        float4* s4 = (float4*)S;
        for (int i = tid; i < KSEL * 2; i += NTHR) s4[i] = gs[i];
        const ulonglong2* gm2 = (const ulonglong2*)(matT + (long long)b * 8 * KSEL);
        ulonglong2* m2 = (ulonglong2*)MT;
        for (int i = tid; i < 4 * KSEL; i += NTHR) m2[i] = gm2[i];
        __syncthreads();

        if (wv == 0) {
            u32 a_bits = 0; // bit w = column (w*64+lane) alive
            #pragma unroll
            for (int w = 0; w < 8; w++)
                if (S[(w * 64 + lane) * 8 + 7] > 0.5f) a_bits |= 1u << w;
            #pragma unroll
            for (int w = 0; w < 8; w++) {
                u64 ow = __ballot((a_bits >> w) & 1u);
                if (lane == 0) sh_ok[w] = ow;
            }
            #pragma unroll 1
            for (int c = 0; c < 8; c++) {
                u64 cross[8];
                #pragma unroll
                for (int w = 0; w < 8; w++) cross[w] = MT[c * KSEL + w * 64 + lane];
                u64 intra = MT[c * KSEL + c * 64 + lane];
                u64 aliveC = __ballot((a_bits >> c) & 1u);
                u32 ilo = (u32)intra, ihi = (u32)(intra >> 32);
                u64 keptC = 0;
                #pragma unroll
                for (int m = 0; m < 64; m++) { // symmetric: row m == lane m's column word
                    u32 rl = __builtin_amdgcn_readlane(ilo, m);
                    u32 rh = __builtin_amdgcn_readlane(ihi, m);
                    u64 rowm = ((u64)rh << 32) | rl;
                    u64 take = (aliveC >> m) & 1ull;
                    u64 msk = (u64)0 - take;
                    keptC |= take << m;
                    aliveC &= ~(rowm & msk);
                }
                if (lane == 0) sh_keep[c] = keptC;
                #pragma unroll
                for (int w = 0; w < 8; w++)
                    if (cross[w] & keptC) a_bits &= ~(1u << w);
            }
        }
        __syncthreads();
        u64 keepW[8], okW[8];
        #pragma unroll
        for (int w = 0; w < 8; w++) { keepW[w] = sh_keep[w]; okW[w] = sh_ok[w]; }

        for (int jj = tid; jj < KSEL; jj += NTHR) { // merge target per column
            int r = jj >> 6, ln = jj & 63;
            int tgt = 0xffff;
            if ((okW[r] >> ln) & 1ull) {
                #pragma unroll
                for (int w = 7; w >= 0; w--) {
                    u64 m = MT[w * KSEL + jj] & keepW[w];
                    if (m) tgt = w * 64 + (int)__builtin_ctzll(m);
                }
            }
            TGT[jj] = (unsigned short)tgt;
        }
        __syncthreads();

        for (int k = tid; k < KSEL; k += NTHR) { // weighted merge per kept row
            int r = k >> 6, ln = k & 63;
            if ((keepW[r] >> ln) & 1ull) {
                float s0 = 0.f, s1 = 0.f, s2 = 0.f, s3 = 0.f, sw = 0.f;
                #pragma unroll 1
                for (int w = 0; w < 8; w++) {
                    u64 m = MT[w * KSEL + k] & okW[w];
                    while (m) {
                        int jj = w * 64 + (int)__builtin_ctzll(m);
                        m &= m - 1;
                        if (TGT[jj] == (unsigned short)k) {
                            float c = S[jj * 8 + 4];
                            s0 += c * S[jj * 8 + 0]; s1 += c * S[jj * 8 + 1];
                            s2 += c * S[jj * 8 + 2]; s3 += c * S[jj * 8 + 3];
                            sw += c;
                        }
                    }
                }
                float d = sw + 1e-12f;
                MG[k * 4 + 0] = s0 / d; MG[k * 4 + 1] = s1 / d;
                MG[k * 4 + 2] = s2 / d; MG[k * 4 + 3] = s3 / d;
            }
        }
        __syncthreads();

        int nk = 0;
        #pragma unroll
        for (int w = 0; w < 8; w++) nk += __popcll(keepW[w]);
        float* ob = out + (long long)b * KSEL * 7;
        for (int i = tid; i < KSEL; i += NTHR) {
            int wi = i >> 6, bi = i & 63;
            if ((keepW[wi] >> bi) & 1ull) {
                int rank = 0;
                for (int w = 0; w < wi; w++) rank += __popcll(keepW[w]);
                rank += __popcll(keepW[wi] & ((1ull << bi) - 1ull));
                float off = S[i * 8 + 6] * 10000.0f;
                float* o = ob + rank * 7;
                o[0] = MG[i * 4 + 0] - off; o[1] = MG[i * 4 + 1];
                o[2] = MG[i * 4 + 2] - off; o[3] = MG[i * 4 + 3];
                o[4] = S[i * 8 + 4]; o[5] = S[i * 8 + 5]; o[6] = S[i * 8 + 6];
            }
        }
        for (int p = nk + tid; p < KSEL; p += NTHR) {
            float* o = ob + p * 7;
            #pragma unroll
            for (int c = 0; c < 7; c++) o[c] = 0.0f;
        }
    }
}

extern "C" void kernel_launch(void* const* d_in, const int* in_sizes, int n_in,
                              void* d_out, int out_size, void* d_ws, size_t ws_size,
                              hipStream_t stream) {
    const float* pred = (const float*)d_in[0];
    float* out = (float*)d_out;
    int total = in_sizes[0];
    int N = total / (BN * ROWF); // 22743
    int totalRows = BN * N;

    char* ws = (char*)d_ws;
    size_t o = 0;
    u32* bar = (u32*)(ws + o);     o += 64;
    u32* hist = (u32*)(ws + o);    o += (size_t)BN * NBKT * 4; // 256 KB
    u32* cnt = (u32*)(ws + o);     o += 128;
    u32* selidx = (u32*)(ws + o);  o += (size_t)BN * KSEL * 4;
    u64* above = (u64*)(ws + o);   o += (size_t)BN * KSEL * 8;
    float* sel = (float*)(ws + o); o += (size_t)BN * KSEL * 8 * 4;
    u64* matT = (u64*)(ws + o);    o += (size_t)BN * KSEL * 8 * 8;
    u32* keys = (u32*)(ws + o);    o += (size_t)totalRows * 4;
    u64* ties = (u64*)(ws + o);    o += (size_t)BN * N * 8;
    (void)ws_size;

    hipMemsetAsync(bar, 0, 64, stream); // reset one-shot grid barriers each call

    coop<<<NBLK, NTHR, 0, stream>>>(pred, keys, hist, cnt, above, ties,
                                    selidx, sel, matT, out, bar, N, totalRows);
}

// Round 8
// 182.424 us; speedup vs baseline: 1.5072x; 1.4997x over previous
//
#include <hip/hip_runtime.h>
#include <stdint.h>

typedef uint32_t u32;
typedef uint64_t u64;

#define BN 16
#define CLS 80
#define ROWF 85
#define KSEL 512
#define NBKT 2048
#define TIE_CAP 4096
#define R1 64
#define CONF_T 0.001f
#define NMS_T 0.5f

__device__ __forceinline__ u32 flip_desc(float x) {
    u32 u = __float_as_uint(x);
    u32 m = (u & 0x80000000u) ? ~u : (u | 0x80000000u); // monotonic ascending
    return ~m;                                          // descending key
}
__device__ __forceinline__ float unflip(u32 key) {
    u32 m = ~key;
    u32 u = (m & 0x80000000u) ? (m & 0x7fffffffu) : ~m;
    return __uint_as_float(u);
}
__device__ __forceinline__ int conf_bucket(float cm) {
    float f = floorf(cm * 2048.0f);
    f = fminf(f, 2047.0f);
    f = fmaxf(f, 0.0f);
    return (int)f;
}

// ---------------- K1: keys + per-image value histogram (LDS-accumulated) ----------------
__global__ __launch_bounds__(256) void k1_keys(const float* __restrict__ pred,
                                               u32* __restrict__ keys,
                                               u32* __restrict__ hist,
                                               int totalRows, int N) {
    __shared__ float stage[R1 * ROWF]; // 21,760 B
    __shared__ u32 lh[NBKT];           // 8,192 B  -> ~5 blocks/CU
    int tid = threadIdx.x;
    int row0 = blockIdx.x * R1;
    int nrow = min(R1, totalRows - row0);
    for (int i = tid; i < NBKT; i += 256) lh[i] = 0;
    int nf4 = nrow * ROWF / 4; // 64|48 rows * 85 -> /4 exact
    const float4* p4 = (const float4*)(pred + (long long)row0 * ROWF);
    float4* b4 = (float4*)stage;
    for (int k = tid; k < nf4; k += 256) b4[k] = p4[k];
    __syncthreads();
    int b0 = row0 / N;
    int split = min(nrow, (b0 + 1) * N - row0); // rows [0,split) -> image b0, rest -> b0+1
    if (tid < nrow) {
        const float* p = &stage[tid * ROWF];
        float obj = p[4];
        float mx = p[5];
        #pragma unroll
        for (int c = 1; c < CLS; c++) { float v = p[5 + c]; if (v > mx) mx = v; }
        float conf = obj * mx;
        float w = p[2], h = p[3];
        bool ok = (conf > CONF_T) && (w > 2.0f) && (w < 10000.0f) && (h > 2.0f) && (h < 10000.0f);
        bool fin = true;
        #pragma unroll
        for (int c = 0; c < ROWF; c++) {
            u32 bb = __float_as_uint(p[c]);
            if ((bb & 0x7f800000u) == 0x7f800000u) fin = false;
        }
        ok = ok && fin;
        float cm = ok ? conf : -1.0f;
        keys[row0 + tid] = flip_desc(cm);
        int bk = conf_bucket(cm);
        if (tid < split) atomicAdd(&lh[bk], 1u);
        else atomicAdd(&hist[(b0 + 1) * NBKT + bk], 1u); // rare straddle rows
    }
    __syncthreads();
    for (int i = tid; i < NBKT; i += 256) {
        u32 v = lh[i];
        if (v) atomicAdd(&hist[b0 * NBKT + i], v);
    }
}

// ---------------- K2: redundant threshold (parallel scan) + compaction slice ----------------
__global__ __launch_bounds__(256) void k2_compact(const u32* __restrict__ keys,
                                                  const u32* __restrict__ hist,
                                                  u32* __restrict__ tbinfo,
                                                  u32* __restrict__ cnt,
                                                  u64* __restrict__ above,
                                                  u64* __restrict__ ties, int N) {
    int b = blockIdx.x >> 4;
    int c = blockIdx.x & 15;
    int tid = threadIdx.x;
    const u32* H = hist + b * NBKT;
    __shared__ u32 scan[256];
    __shared__ u32 sh_Tb, sh_nA;
    u32 hloc[8];
    u32 s = 0;
    #pragma unroll
    for (int k = 0; k < 8; k++) { hloc[k] = H[NBKT - 1 - (tid * 8 + k)]; s += hloc[k]; }
    // inclusive Hillis-Steele scan over 256 partials (suffix-from-top order)
    u32 v = s;
    for (int off = 1; off < 256; off <<= 1) {
        scan[tid] = v;
        __syncthreads();
        u32 add = (tid >= off) ? scan[tid - off] : 0u;
        __syncthreads();
        v += add;
    }
    u32 excl = v - s;
    if (excl < KSEL && v >= KSEL) { // unique crossing thread
        u32 cum = excl;
        #pragma unroll
        for (int k = 0; k < 8; k++) {
            int bidx = NBKT - 1 - (tid * 8 + k);
            if (cum + hloc[k] >= KSEL) { sh_Tb = (u32)bidx; sh_nA = cum; break; }
            cum += hloc[k];
        }
    }
    __syncthreads();
    u32 Tb = sh_Tb;
    if (c == 0 && tid == 0) { tbinfo[b * 2] = Tb; tbinfo[b * 2 + 1] = sh_nA; }
    // compact this block's slice
    int CH = (N + 15) / 16;
    const u32* kk = keys + (long long)b * N;
    u64* av = above + b * KSEL;
    u64* tv = ties + (long long)b * N;
    int end = min(N, (c + 1) * CH);
    for (int i = c * CH + tid; i < end; i += 256) {
        u32 e = kk[i];
        u32 bk = (u32)conf_bucket(unflip(e));
        if (bk > Tb) {
            u32 p = atomicAdd(&cnt[b * 2], 1u);
            av[p] = ((u64)e << 32) | (u32)i;
        } else if (bk == Tb) {
            u32 p = atomicAdd(&cnt[b * 2 + 1], 1u);
            tv[p] = ((u64)e << 32) | (u32)i;
        }
    }
}

// ---------------- K3: rank-select + gather + IoU + NMS scan + merge + output ----------------
__global__ __launch_bounds__(512) void k3_nms(const float* __restrict__ pred,
                                              const u64* __restrict__ above,
                                              const u64* __restrict__ ties,
                                              const u32* __restrict__ tbinfo,
                                              const u32* __restrict__ cnt,
                                              float* __restrict__ out, int N) {
    int b = blockIdx.x;
    int tid = threadIdx.x;
    int lane = tid & 63;
    int wv = tid >> 6;
    __shared__ __align__(16) unsigned char LDSU[58368]; // 57 KB union
    __shared__ u64 sh_keep[8], sh_ok[8];
    float* S = (float*)LDSU;                               // [0, 16384)
    u64* MT = (u64*)(LDSU + 16384);                        // [16384, 49152)  [w][i]
    float* MG = (float*)(LDSU + 49152);                    // [49152, 57344)
    u64* skey = (u64*)(LDSU + 49152);                      // 4 KB (dead before MG written)
    unsigned short* TGT = (unsigned short*)(LDSU + 57344); // [57344, 58368)
    u64* tieL = (u64*)LDSU;                                // 32 KB (dead before S written)
    u64* abvL = (u64*)(LDSU + 32768);                      // 4 KB (dead before MT written)

    // ---- phase A: counting-rank placement (replaces radix-select + bitonic) ----
    u32 nA = tbinfo[b * 2 + 1];
    u32 ntie = cnt[b * 2 + 1];
    u32 tsel = KSEL - nA;
    const u64* av = above + b * KSEL;
    const u64* tv = ties + (long long)b * N;
    for (u32 i = tid; i < nA; i += 512) abvL[i] = av[i];
    bool lds_ties = (ntie <= TIE_CAP);
    if (lds_ties) for (u32 i = tid; i < ntie; i += 512) tieL[i] = tv[i];
    __syncthreads();
    if (tid < (int)nA) { // all u64 distinct (low 32 = unique idx) -> rank is a bijection
        u64 e = abvL[tid];
        u32 r = 0;
        for (u32 k = 0; k < nA; k++) r += (abvL[k] < e) ? 1u : 0u;
        skey[r] = e;
    }
    for (u32 jj = tid; jj < ntie; jj += 512) {
        u64 e = lds_ties ? tieL[jj] : tv[jj];
        u32 r = 0;
        if (lds_ties) { for (u32 k = 0; k < ntie; k++) r += (tieL[k] < e) ? 1u : 0u; }
        else          { for (u32 k = 0; k < ntie; k++) r += (tv[k]  < e) ? 1u : 0u; }
        if (r < tsel) skey[nA + r] = e; // asc u64 == conf desc, idx asc == lax.top_k
    }
    __syncthreads();

    // ---- phase B: gather rows -> S ----
    {
        int idx = (int)(skey[tid] & 0xffffffffu);
        const float* row = pred + ((long long)b * N + idx) * ROWF;
        float obj = row[4];
        float mx = row[5]; int am = 0;
        for (int c = 1; c < CLS; c++) { float v = row[5 + c]; if (v > mx) { mx = v; am = c; } }
        float conf = obj * mx;
        float cx = row[0], cy = row[1], w = row[2], h = row[3];
        bool ok = (conf > CONF_T) && (w > 2.0f) && (w < 10000.0f) && (h > 2.0f) && (h < 10000.0f);
        bool fin = true;
        for (int c = 0; c < ROWF; c++) {
            u32 bb = __float_as_uint(row[c]);
            if ((bb & 0x7f800000u) == 0x7f800000u) fin = false;
        }
        ok = ok && fin;
        float off = (float)am * 10000.0f;
        float x1 = cx - w * 0.5f, y1 = cy - h * 0.5f;
        float x2 = cx + w * 0.5f, y2 = cy + h * 0.5f;
        float* s = &S[tid * 8];
        s[0] = x1 + off; s[1] = y1; s[2] = x2 + off; s[3] = y2;
        s[4] = conf; s[5] = mx; s[6] = (float)am; s[7] = ok ? 1.0f : 0.0f;
    }
    __syncthreads();

    // ---- phase C: IoU bitmatrix -> MT; (w,jj) wave-uniform => LDS broadcasts ----
    {
        int i = tid;
        float x1 = S[i * 8 + 0], y1 = S[i * 8 + 1], x2 = S[i * 8 + 2], y2 = S[i * 8 + 3];
        float a1 = __fmul_rn(__fsub_rn(x2, x1), __fsub_rn(y2, y1));
        #pragma unroll 1
        for (int w = 0; w < 8; w++) {
            u64 bits = 0;
            int j0 = w * 64;
            for (int jj2 = 0; jj2 < 64; jj2++) {
                const float* bj = &S[(j0 + jj2) * 8];
                float ix = fmaxf(__fsub_rn(fminf(x2, bj[2]), fmaxf(x1, bj[0])), 0.0f);
                float iy = fmaxf(__fsub_rn(fminf(y2, bj[3]), fmaxf(y1, bj[1])), 0.0f);
                float inter = __fmul_rn(ix, iy);
                float a2 = __fmul_rn(__fsub_rn(bj[2], bj[0]), __fsub_rn(bj[3], bj[1]));
                float denom = __fadd_rn(__fsub_rn(__fadd_rn(a1, a2), inter), 1e-9f);
                float iou = __fdiv_rn(inter, denom);
                if (iou > NMS_T) bits |= (1ull << jj2);
            }
            MT[w * KSEL + i] = bits;
        }
    }
    __syncthreads();

    // ---- phase D: chunked scalar keep-scan (wave 0) ----
    if (wv == 0) {
        u32 a_bits = 0; // bit w = column (w*64+lane) alive
        #pragma unroll
        for (int w = 0; w < 8; w++)
            if (S[(w * 64 + lane) * 8 + 7] > 0.5f) a_bits |= 1u << w;
        #pragma unroll
        for (int w = 0; w < 8; w++) {
            u64 ow = __ballot((a_bits >> w) & 1u);
            if (lane == 0) sh_ok[w] = ow;
        }
        #pragma unroll 1
        for (int c = 0; c < 8; c++) {
            u64 cross[8];
            #pragma unroll
            for (int w = 0; w < 8; w++) cross[w] = MT[c * KSEL + w * 64 + lane];
            u64 intra = MT[c * KSEL + c * 64 + lane];
            u64 aliveC = __ballot((a_bits >> c) & 1u);
            u32 ilo = (u32)intra, ihi = (u32)(intra >> 32);
            u64 keptC = 0;
            #pragma unroll
            for (int m = 0; m < 64; m++) { // symmetric: row m == lane m's column word
                u32 rl = __builtin_amdgcn_readlane(ilo, m);
                u32 rh = __builtin_amdgcn_readlane(ihi, m);
                u64 rowm = ((u64)rh << 32) | rl;
                u64 take = (aliveC >> m) & 1ull;
                u64 msk = (u64)0 - take;
                keptC |= take << m;
                aliveC &= ~(rowm & msk);
            }
            if (lane == 0) sh_keep[c] = keptC;
            #pragma unroll
            for (int w = 0; w < 8; w++)
                if (cross[w] & keptC) a_bits &= ~(1u << w);
        }
    }
    __syncthreads();
    u64 keepW[8], okW[8];
    #pragma unroll
    for (int w = 0; w < 8; w++) { keepW[w] = sh_keep[w]; okW[w] = sh_ok[w]; }

    // ---- phase E1: per-column merge target = first kept bit of row j (M symmetric) ----
    {
        int j = tid;
        int r = j >> 6, ln = j & 63;
        int tgt = 0xffff;
        if ((okW[r] >> ln) & 1ull) {
            #pragma unroll
            for (int w = 7; w >= 0; w--) {
                u64 m = MT[w * KSEL + j] & keepW[w];
                if (m) tgt = w * 64 + (int)__builtin_ctzll(m);
            }
        }
        TGT[j] = (unsigned short)tgt;
    }
    __syncthreads();

    // ---- phase E2: per kept k, deterministic ascending-j weighted merge ----
    {
        int k = tid;
        int r = k >> 6, ln = k & 63;
        if ((keepW[r] >> ln) & 1ull) {
            float s0 = 0.f, s1 = 0.f, s2 = 0.f, s3 = 0.f, sw = 0.f;
            #pragma unroll 1
            for (int w = 0; w < 8; w++) {
                u64 m = MT[w * KSEL + k] & okW[w];
                while (m) {
                    int j = w * 64 + (int)__builtin_ctzll(m);
                    m &= m - 1;
                    if (TGT[j] == (unsigned short)k) {
                        float c = S[j * 8 + 4];
                        s0 += c * S[j * 8 + 0]; s1 += c * S[j * 8 + 1];
                        s2 += c * S[j * 8 + 2]; s3 += c * S[j * 8 + 3];
                        sw += c;
                    }
                }
            }
            float d = sw + 1e-12f;
            MG[k * 4 + 0] = s0 / d; MG[k * 4 + 1] = s1 / d;
            MG[k * 4 + 2] = s2 / d; MG[k * 4 + 3] = s3 / d;
        }
    }
    __syncthreads();

    // ---- output: compact kept rows in order, zero tail ----
    int nk = 0;
    #pragma unroll
    for (int w = 0; w < 8; w++) nk += __popcll(keepW[w]);
    float* ob = out + (long long)b * KSEL * 7;
    {
        int i = tid;
        int wi = i >> 6, bi = i & 63;
        if ((keepW[wi] >> bi) & 1ull) {
            int rank = 0;
            for (int w = 0; w < wi; w++) rank += __popcll(keepW[w]);
            rank += __popcll(keepW[wi] & ((1ull << bi) - 1ull));
            float off = S[i * 8 + 6] * 10000.0f;
            float* o = ob + rank * 7;
            o[0] = MG[i * 4 + 0] - off; o[1] = MG[i * 4 + 1];
            o[2] = MG[i * 4 + 2] - off; o[3] = MG[i * 4 + 3];
            o[4] = S[i * 8 + 4]; o[5] = S[i * 8 + 5]; o[6] = S[i * 8 + 6];
        }
    }
    for (int p = nk + tid; p < KSEL; p += 512) {
        float* o = ob + p * 7;
        #pragma unroll
        for (int c = 0; c < 7; c++) o[c] = 0.0f;
    }
}

extern "C" void kernel_launch(void* const* d_in, const int* in_sizes, int n_in,
                              void* d_out, int out_size, void* d_ws, size_t ws_size,
                              hipStream_t stream) {
    const float* pred = (const float*)d_in[0];
    float* out = (float*)d_out;
    int total = in_sizes[0];
    int N = total / (BN * ROWF); // 22743
    int totalRows = BN * N;

    char* ws = (char*)d_ws;
    size_t o = 0;
    u32* hist = (u32*)(ws + o);   o += (size_t)BN * NBKT * 4; // 128 KB
    u32* cnt = (u32*)(ws + o);    o += 128;
    u32* tbinfo = (u32*)(ws + o); o += 128;
    u32* keys = (u32*)(ws + o);   o += (size_t)totalRows * 4;
    u64* above = (u64*)(ws + o);  o += (size_t)BN * KSEL * 8;
    u64* ties = (u64*)(ws + o);   o += (size_t)BN * N * 8;
    (void)ws_size;

    hipMemsetAsync(hist, 0, (size_t)BN * NBKT * 4 + 128, stream); // zero hist + cnt

    k1_keys<<<(totalRows + R1 - 1) / R1, 256, 0, stream>>>(pred, keys, hist, totalRows, N);
    k2_compact<<<BN * 16, 256, 0, stream>>>(keys, hist, tbinfo, cnt, above, ties, N);
    k3_nms<<<BN, 512, 0, stream>>>(pred, above, ties, tbinfo, cnt, out, N);
}